// Round 13
// baseline (91.201 us; speedup 1.0000x reference)
//
#include <hip/hip_runtime.h>

#define LOG2E 1.4426950408889634f
#define TWO_LOG2E 2.885390081777927f

__device__ __forceinline__ float fast_exp2(float x) { return __builtin_amdgcn_exp2f(x); }
__device__ __forceinline__ float fast_rcp(float x)  { return __builtin_amdgcn_rcpf(x); }

// ---------------------------------------------------------------------------
// K1: projections + exp transform. Virtual M=4096 rows: blocks 0..255 ->
// exp2(2*log2e * query*Wq) -> eq, blocks 256..511 -> value*Wv -> ek.
// ---------------------------------------------------------------------------
__global__ __launch_bounds__(256) void proj_kernel(
    const float* __restrict__ query, const float* __restrict__ value,
    const float* __restrict__ Wq, const float* __restrict__ Wv,
    float* __restrict__ eq, float* __restrict__ ek)
{
    __shared__ float in_lds[8 * 256];
    const int t = threadIdx.x;
    const int row0 = blockIdx.x * 8;
    const float* src; const float* W; float* dst;
    if (row0 < 2048) { src = query + (size_t)row0 * 256; W = Wq; dst = eq + (size_t)row0 * 256; }
    else { const int r = row0 - 2048; src = value + (size_t)r * 256; W = Wv; dst = ek + (size_t)r * 256; }

    const float4* s4 = (const float4*)src;
    float4* l4 = (float4*)in_lds;
    l4[t] = s4[t];
    l4[t + 256] = s4[t + 256];
    __syncthreads();

    float acc[8];
#pragma unroll
    for (int r = 0; r < 8; ++r) acc[r] = 0.f;

    for (int d = 0; d < 256; d += 4) {
        const float w0 = W[(d + 0) * 256 + t];
        const float w1 = W[(d + 1) * 256 + t];
        const float w2 = W[(d + 2) * 256 + t];
        const float w3 = W[(d + 3) * 256 + t];
#pragma unroll
        for (int r = 0; r < 8; ++r) {
            const float4 v = *(const float4*)&in_lds[r * 256 + d];
            acc[r] = fmaf(v.x, w0, acc[r]);
            acc[r] = fmaf(v.y, w1, acc[r]);
            acc[r] = fmaf(v.z, w2, acc[r]);
            acc[r] = fmaf(v.w, w3, acc[r]);
        }
    }
#pragma unroll
    for (int r = 0; r < 8; ++r) dst[r * 256 + t] = fast_exp2(acc[r] * TWO_LOG2E);
}

// ---------------------------------------------------------------------------
// K2: FUSED scores + softmax + PV, v2 (corrected).
// Block = (b, 4 q-rows), 512 thr (8 waves), grid (128,4)=512 blocks, ~71KB
// LDS -> 2 blocks/CU (16 waves/CU). Wave w = (q = w>>1, d-half h = w&1).
// Stride 258 == 2 (mod 32): per-lane-row b64 reads hit 16 even start banks
// x 4 lanes (ideal); wave-uniform-row b128 staging stores 8 req/bank (ideal).
// No swizzle needed.
// Phase A (fully unrolled over 8 k-tiles): thread computes d-half-h partial
//   score for k = 64*tt+lane with FOUR independent chains (d,d+32,d+64,d+96)
//   -> ILP hides the rcp dependency. e[8] register-resident.
// Phase B: combine halves in s_lds (overlay on ek_lds), per-wave softmax
//   (shfl), write normalized attn, raw exp stays in s_lds, inv -> inv_lds.
// Phase C: PV: wave w owns k in [64w,64w+64): coalesced global value loads,
//   broadcast b128 s_lds reads, acc[4 rows] x float4.
// Phase D: cross-wave tree reduce on red (= ek_lds + 4096; disjoint).
// ---------------------------------------------------------------------------
#define EK_ST 258
#define EQ_ST 258
#define SS_ST 520
__global__ __launch_bounds__(512) void fused_kernel(
    const float* __restrict__ eq, const float* __restrict__ ek,
    const float* __restrict__ scale, const float* __restrict__ value,
    float* __restrict__ attn, float* __restrict__ out)
{
    __shared__ float ek_lds[64 * EK_ST];   // 66KB; overlaid in B/D
    __shared__ float eq_lds[4 * EQ_ST];
    __shared__ float sc_lds[256];
    __shared__ float inv_lds[4];

    const int t = threadIdx.x;
    const int w = t >> 6, lane = t & 63;
    const int q = w >> 1, h = w & 1;
    const int dbase = 128 * h;
    const int qt = blockIdx.x, b = blockIdx.y;
    const int q0 = qt * 4;

    // stage eq (4 rows x 256) and scale
    if (t < 256) {
        const float4 v = ((const float4*)(eq + (size_t)(b * 512 + q0) * 256))[t];
        *(float4*)&eq_lds[(t >> 6) * EQ_ST + (t & 63) * 4] = v;
    } else {
        sc_lds[t - 256] = -2.f * scale[t - 256];
    }

    float e[8];
    const float* ekb = ek + (size_t)(b * 512) * 256;
    const float* eqrow = &eq_lds[q * EQ_ST + dbase];
    const float* scp = &sc_lds[dbase];
    const float* kr = &ek_lds[lane * EK_ST + dbase];

    // ---- Phase A (tt fully unrolled so e[tt] stays in registers) ----
#pragma unroll
    for (int tt = 0; tt < 8; ++tt) {
        __syncthreads();
        {   // stage tile tt: 64 rows x 64 float4s; row is wave-uniform
            const float4* src = (const float4*)(ekb + (size_t)(64 * tt) * 256);
#pragma unroll
            for (int l = 0; l < 8; ++l) {
                const int row = w + 8 * l;
                *(float4*)&ek_lds[row * EK_ST + lane * 4] = src[(size_t)row * 64 + lane];
            }
        }
        __syncthreads();

        float a0 = 0.f, a1 = 0.f, a2 = 0.f, a3 = 0.f;
#pragma unroll 8
        for (int d = 0; d < 32; d += 2) {
            const float2 s_0 = *(const float2*)&scp[d];
            const float2 s_1 = *(const float2*)&scp[d + 32];
            const float2 s_2 = *(const float2*)&scp[d + 64];
            const float2 s_3 = *(const float2*)&scp[d + 96];
            const float2 q_0 = *(const float2*)&eqrow[d];
            const float2 q_1 = *(const float2*)&eqrow[d + 32];
            const float2 q_2 = *(const float2*)&eqrow[d + 64];
            const float2 q_3 = *(const float2*)&eqrow[d + 96];
            const float2 k_0 = *(const float2*)&kr[d];
            const float2 k_1 = *(const float2*)&kr[d + 32];
            const float2 k_2 = *(const float2*)&kr[d + 64];
            const float2 k_3 = *(const float2*)&kr[d + 96];

            {
                const float A = fmaf(q_0.x, k_0.x, 1.f), B = fmaf(q_0.y, k_0.y, 1.f);
                a0 = fmaf(fmaf(s_0.y, A, s_0.x * B), fast_rcp(A * B), a0);
            }
            {
                const float A = fmaf(q_1.x, k_1.x, 1.f), B = fmaf(q_1.y, k_1.y, 1.f);
                a1 = fmaf(fmaf(s_1.y, A, s_1.x * B), fast_rcp(A * B), a1);
            }
            {
                const float A = fmaf(q_2.x, k_2.x, 1.f), B = fmaf(q_2.y, k_2.y, 1.f);
                a2 = fmaf(fmaf(s_2.y, A, s_2.x * B), fast_rcp(A * B), a2);
            }
            {
                const float A = fmaf(q_3.x, k_3.x, 1.f), B = fmaf(q_3.y, k_3.y, 1.f);
                a3 = fmaf(fmaf(s_3.y, A, s_3.x * B), fast_rcp(A * B), a3);
            }
        }
        e[tt] = (a0 + a1) + (a2 + a3);
    }

    // ---- Phase B: combine d-halves, softmax, attn write ----
    float* s_lds = ek_lds;                 // overlay: 4 x SS_ST = 2080 floats
    __syncthreads();
    if (h == 0) {
#pragma unroll
        for (int tt = 0; tt < 8; ++tt) s_lds[q * SS_ST + 64 * tt + lane] = e[tt];
    }
    __syncthreads();
    if (h == 1) {
#pragma unroll
        for (int tt = 0; tt < 8; ++tt) {
            const int idx = q * SS_ST + 64 * tt + lane;
            s_lds[idx] = s_lds[idx] + e[tt];
        }
    }
    __syncthreads();

    float x[8];
    float m = -1e30f;
#pragma unroll
    for (int j = 0; j < 8; ++j) {
        x[j] = s_lds[q * SS_ST + 64 * j + lane];
        m = fmaxf(m, x[j]);
    }
#pragma unroll
    for (int off = 32; off; off >>= 1) m = fmaxf(m, __shfl_xor(m, off));

    float sum = 0.f;
#pragma unroll
    for (int j = 0; j < 8; ++j) { x[j] = fast_exp2((x[j] - m) * LOG2E); sum += x[j]; }
#pragma unroll
    for (int off = 32; off; off >>= 1) sum += __shfl_xor(sum, off);
    const float inv = fast_rcp(sum);

    float* arow = attn + (size_t)(b * 512 + q0 + q) * 512;
#pragma unroll
    for (int j = 0; j < 4; ++j) {
        const int jj = 4 * h + j;
        s_lds[q * SS_ST + 64 * jj + lane] = x[jj];
        arow[64 * jj + lane] = x[jj] * inv;
    }
    if (h == 0 && lane == 0) inv_lds[q] = inv;
    __syncthreads();

    // ---- Phase C: PV, wave w owns k in [64w, 64w+64) ----
    float4 acc[4];
#pragma unroll
    for (int r = 0; r < 4; ++r) acc[r] = make_float4(0.f, 0.f, 0.f, 0.f);

    const float* vbase = value + (size_t)(b * 512 + 64 * w) * 256;
    for (int k4 = 0; k4 < 64; k4 += 4) {
        const float4 v0 = *(const float4*)&vbase[(k4 + 0) * 256 + lane * 4];
        const float4 v1 = *(const float4*)&vbase[(k4 + 1) * 256 + lane * 4];
        const float4 v2 = *(const float4*)&vbase[(k4 + 2) * 256 + lane * 4];
        const float4 v3 = *(const float4*)&vbase[(k4 + 3) * 256 + lane * 4];
#pragma unroll
        for (int r = 0; r < 4; ++r) {
            const float4 s4 = *(const float4*)&s_lds[r * SS_ST + 64 * w + k4];
            acc[r].x = fmaf(s4.x, v0.x, acc[r].x); acc[r].y = fmaf(s4.x, v0.y, acc[r].y);
            acc[r].z = fmaf(s4.x, v0.z, acc[r].z); acc[r].w = fmaf(s4.x, v0.w, acc[r].w);
            acc[r].x = fmaf(s4.y, v1.x, acc[r].x); acc[r].y = fmaf(s4.y, v1.y, acc[r].y);
            acc[r].z = fmaf(s4.y, v1.z, acc[r].z); acc[r].w = fmaf(s4.y, v1.w, acc[r].w);
            acc[r].x = fmaf(s4.z, v2.x, acc[r].x); acc[r].y = fmaf(s4.z, v2.y, acc[r].y);
            acc[r].z = fmaf(s4.z, v2.z, acc[r].z); acc[r].w = fmaf(s4.z, v2.w, acc[r].w);
            acc[r].x = fmaf(s4.w, v3.x, acc[r].x); acc[r].y = fmaf(s4.w, v3.y, acc[r].y);
            acc[r].z = fmaf(s4.w, v3.z, acc[r].z); acc[r].w = fmaf(s4.w, v3.w, acc[r].w);
        }
    }

    // ---- Phase D: tree reduce 8 -> 1 (red disjoint from s_lds) ----
    float* red = ek_lds + 4096;
    if (w >= 4) {
#pragma unroll
        for (int r = 0; r < 4; ++r)
            *(float4*)&red[((w - 4) * 4 + r) * 256 + lane * 4] = acc[r];
    }
    __syncthreads();
    if (w < 4) {
#pragma unroll
        for (int r = 0; r < 4; ++r) {
            const float4 o = *(const float4*)&red[(w * 4 + r) * 256 + lane * 4];
            acc[r].x += o.x; acc[r].y += o.y; acc[r].z += o.z; acc[r].w += o.w;
        }
    }
    __syncthreads();
    if (w >= 2 && w < 4) {
#pragma unroll
        for (int r = 0; r < 4; ++r)
            *(float4*)&red[((w - 2) * 4 + r) * 256 + lane * 4] = acc[r];
    }
    __syncthreads();
    if (w < 2) {
#pragma unroll
        for (int r = 0; r < 4; ++r) {
            const float4 o = *(const float4*)&red[(w * 4 + r) * 256 + lane * 4];
            acc[r].x += o.x; acc[r].y += o.y; acc[r].z += o.z; acc[r].w += o.w;
        }
    }
    __syncthreads();
    if (w == 1) {
#pragma unroll
        for (int r = 0; r < 4; ++r)
            *(float4*)&red[r * 256 + lane * 4] = acc[r];
    }
    __syncthreads();
    if (w == 0) {
#pragma unroll
        for (int r = 0; r < 4; ++r) {
            const float4 o = *(const float4*)&red[r * 256 + lane * 4];
            const float iv = inv_lds[r];
            float4 res;
            res.x = (acc[r].x + o.x) * iv;
            res.y = (acc[r].y + o.y) * iv;
            res.z = (acc[r].z + o.z) * iv;
            res.w = (acc[r].w + o.w) * iv;
            *(float4*)&out[(size_t)(b * 512 + q0 + r) * 256 + lane * 4] = res;
        }
    }
}

extern "C" void kernel_launch(void* const* d_in, const int* in_sizes, int n_in,
                              void* d_out, int out_size, void* d_ws, size_t ws_size,
                              hipStream_t stream) {
    const float* query = (const float*)d_in[0];
    const float* value = (const float*)d_in[1];
    const float* Wq    = (const float*)d_in[2];
    const float* Wv    = (const float*)d_in[3];
    const float* scale = (const float*)d_in[4];

    float* out0 = (float*)d_out;                 // [4,512,256]
    float* attn = out0 + 4 * 512 * 256;          // [4,512,512]

    float* eq = (float*)d_ws;                    // [2048,256]
    float* ek = eq + 2048 * 256;                 // [2048,256]

    proj_kernel<<<512, 256, 0, stream>>>(query, value, Wq, Wv, eq, ek);
    fused_kernel<<<dim3(128, 4), 512, 0, stream>>>(eq, ek, scale, value, attn, out0);
}

// Round 14
// 67.168 us; speedup vs baseline: 1.3578x; 1.3578x over previous
//
#include <hip/hip_runtime.h>

#define LOG2E 1.4426950408889634f
#define TWO_LOG2E 2.885390081777927f

__device__ __forceinline__ float fast_exp2(float x) { return __builtin_amdgcn_exp2f(x); }
__device__ __forceinline__ float fast_rcp(float x)  { return __builtin_amdgcn_rcpf(x); }

// paired-rcp: s0/(A)+s1/(B) with A=q0*k0+1, B=q1*k1+1
__device__ __forceinline__ void term2(float s0, float s1, float qx, float qy,
                                      float kx, float ky, float& acc) {
    const float A = fmaf(qx, kx, 1.f);
    const float B = fmaf(qy, ky, 1.f);
    acc = fmaf(fmaf(s1, A, s0 * B), fast_rcp(A * B), acc);
}

// ---------------------------------------------------------------------------
// K1: projections + exp transform (unchanged). blocks 0..255 -> eq,
// 256..511 -> ek; 8 rows per block, 256 threads.
// ---------------------------------------------------------------------------
__global__ __launch_bounds__(256) void proj_kernel(
    const float* __restrict__ query, const float* __restrict__ value,
    const float* __restrict__ Wq, const float* __restrict__ Wv,
    float* __restrict__ eq, float* __restrict__ ek)
{
    __shared__ float in_lds[8 * 256];
    const int t = threadIdx.x;
    const int row0 = blockIdx.x * 8;
    const float* src; const float* W; float* dst;
    if (row0 < 2048) { src = query + (size_t)row0 * 256; W = Wq; dst = eq + (size_t)row0 * 256; }
    else { const int r = row0 - 2048; src = value + (size_t)r * 256; W = Wv; dst = ek + (size_t)r * 256; }

    const float4* s4 = (const float4*)src;
    float4* l4 = (float4*)in_lds;
    l4[t] = s4[t];
    l4[t + 256] = s4[t + 256];
    __syncthreads();

    float acc[8];
#pragma unroll
    for (int r = 0; r < 8; ++r) acc[r] = 0.f;

    for (int d = 0; d < 256; d += 4) {
        const float w0 = W[(d + 0) * 256 + t];
        const float w1 = W[(d + 1) * 256 + t];
        const float w2 = W[(d + 2) * 256 + t];
        const float w3 = W[(d + 3) * 256 + t];
#pragma unroll
        for (int r = 0; r < 8; ++r) {
            const float4 v = *(const float4*)&in_lds[r * 256 + d];
            acc[r] = fmaf(v.x, w0, acc[r]);
            acc[r] = fmaf(v.y, w1, acc[r]);
            acc[r] = fmaf(v.z, w2, acc[r]);
            acc[r] = fmaf(v.w, w3, acc[r]);
        }
    }
#pragma unroll
    for (int r = 0; r < 8; ++r) dst[r * 256 + t] = fast_exp2(acc[r] * TWO_LOG2E);
}

// ---------------------------------------------------------------------------
// K2: FUSED scores + softmax + PV, v3 (octant / register-tiled).
// Block = (b, 8 q-rows), 512 thr (8 waves), grid (64,4) = 256 blocks (1/CU).
// Thread = (d-octant = wave w: 32 d), q-pair qp = lane>>4, k-quad kq = lane&15.
//   -> 2q x 4k x 4d per iteration: 7 b128 LDS reads per 32 elements (2.6
//   LDS-cyc/elem vs 9.75 in the per-thread-score version; this kernel is
//   LDS-issue-bound).
// ek tile (64 x 256) swizzled: row r chunk c stored at (c + (r>>2)) & 63,
// stride 260 -> the 4 k-row b128 reads land on 8 bank-groups (2-way = free);
// staging writes stay 1KB-coalesced from global.
// Per tile: compute -> pslot partial (8 octants) -> barrier -> stage next
// tile + deterministic per-score sum into s_tile (2 barriers/tile total).
// Then R10-proven: softmax (wave=row) -> PV (wave owns 64 k) -> tree reduce.
// LDS ~109KB -> 1 block/CU.
// ---------------------------------------------------------------------------
#define EK_ST 260
#define EQ_ST 260
#define SS_ST 520
__global__ __launch_bounds__(512) void fused_kernel(
    const float* __restrict__ eq, const float* __restrict__ ek,
    const float* __restrict__ scale, const float* __restrict__ value,
    float* __restrict__ attn, float* __restrict__ out)
{
    __shared__ float ek_lds[64 * EK_ST];    // 65KB; reduce buffer in Phase D
    __shared__ float eq_lds[8 * EQ_ST];
    __shared__ float sc_lds[256];
    __shared__ float s_tile[8 * SS_ST];     // raw scores -> raw exp
    __shared__ float pslot[8 * SS_ST];      // octant partials per tile
    __shared__ float inv_lds[8];

    const int t = threadIdx.x;
    const int w = t >> 6, lane = t & 63;
    const int qp = lane >> 4;               // q-pair 0..3
    const int kq = lane & 15;               // k-quad 0..15
    const int ds = 32 * w;                  // d-octant base
    const int qt = blockIdx.x, b = blockIdx.y;
    const int q0 = qt * 8;

    const float* ekb = ek + (size_t)(b * 512) * 256;

    // prologue: stage eq (8x256: 512 chunks, 1/thread), scale, ek tile 0
    {
        const int row = t >> 6, c = t & 63;
        const float4 v = ((const float4*)(eq + (size_t)(b * 512 + q0) * 256))[row * 64 + c];
        *(float4*)&eq_lds[row * EQ_ST + 4 * c] = v;
    }
    if (t < 256) sc_lds[t] = -2.f * scale[t];
    {
        const float4* src = (const float4*)ekb;   // tile 0
#pragma unroll
        for (int l = 0; l < 8; ++l) {
            const int row = 8 * l + w;
            const int cc = 4 * ((lane + (row >> 2)) & 63);
            *(float4*)&ek_lds[row * EK_ST + cc] = src[row * 64 + lane];
        }
    }
    __syncthreads();

    // ---- Phase A: 8 k-tiles ----
#pragma unroll
    for (int tt = 0; tt < 8; ++tt) {
        float a00 = 0.f, a01 = 0.f, a02 = 0.f, a03 = 0.f;
        float a10 = 0.f, a11 = 0.f, a12 = 0.f, a13 = 0.f;

#pragma unroll
        for (int it = 0; it < 8; ++it) {
            const int d = ds + 4 * it;
            const float4 sv = *(const float4*)&sc_lds[d];
            const float4 q0v = *(const float4*)&eq_lds[(2 * qp + 0) * EQ_ST + d];
            const float4 q1v = *(const float4*)&eq_lds[(2 * qp + 1) * EQ_ST + d];
            const int cc = 4 * (((d >> 2) + kq) & 63);
            const float4 k0 = *(const float4*)&ek_lds[(4 * kq + 0) * EK_ST + cc];
            const float4 k1 = *(const float4*)&ek_lds[(4 * kq + 1) * EK_ST + cc];
            const float4 k2 = *(const float4*)&ek_lds[(4 * kq + 2) * EK_ST + cc];
            const float4 k3 = *(const float4*)&ek_lds[(4 * kq + 3) * EK_ST + cc];

            term2(sv.x, sv.y, q0v.x, q0v.y, k0.x, k0.y, a00);
            term2(sv.x, sv.y, q0v.x, q0v.y, k1.x, k1.y, a01);
            term2(sv.x, sv.y, q0v.x, q0v.y, k2.x, k2.y, a02);
            term2(sv.x, sv.y, q0v.x, q0v.y, k3.x, k3.y, a03);
            term2(sv.x, sv.y, q1v.x, q1v.y, k0.x, k0.y, a10);
            term2(sv.x, sv.y, q1v.x, q1v.y, k1.x, k1.y, a11);
            term2(sv.x, sv.y, q1v.x, q1v.y, k2.x, k2.y, a12);
            term2(sv.x, sv.y, q1v.x, q1v.y, k3.x, k3.y, a13);

            term2(sv.z, sv.w, q0v.z, q0v.w, k0.z, k0.w, a00);
            term2(sv.z, sv.w, q0v.z, q0v.w, k1.z, k1.w, a01);
            term2(sv.z, sv.w, q0v.z, q0v.w, k2.z, k2.w, a02);
            term2(sv.z, sv.w, q0v.z, q0v.w, k3.z, k3.w, a03);
            term2(sv.z, sv.w, q1v.z, q1v.w, k0.z, k0.w, a10);
            term2(sv.z, sv.w, q1v.z, q1v.w, k1.z, k1.w, a11);
            term2(sv.z, sv.w, q1v.z, q1v.w, k2.z, k2.w, a12);
            term2(sv.z, sv.w, q1v.z, q1v.w, k3.z, k3.w, a13);
        }

        // octant partials -> pslot[w][score]
        {
            float* ps = &pslot[w * SS_ST];
            const int s0i = (2 * qp + 0) * 64 + 4 * kq;
            const int s1i = (2 * qp + 1) * 64 + 4 * kq;
            ps[s0i + 0] = a00; ps[s0i + 1] = a01; ps[s0i + 2] = a02; ps[s0i + 3] = a03;
            ps[s1i + 0] = a10; ps[s1i + 1] = a11; ps[s1i + 2] = a12; ps[s1i + 3] = a13;
        }
        __syncthreads();                       // B2: ek reads + pslot writes done

        if (tt < 7) {                          // stage next tile
            const float4* src = (const float4*)(ekb + (size_t)(64 * (tt + 1)) * 256);
#pragma unroll
            for (int l = 0; l < 8; ++l) {
                const int row = 8 * l + w;
                const int cc = 4 * ((lane + (row >> 2)) & 63);
                *(float4*)&ek_lds[row * EK_ST + cc] = src[row * 64 + lane];
            }
        }
        // deterministic sum of 8 octant partials; thread t owns score t
        {
            float s = pslot[t];
#pragma unroll
            for (int o = 1; o < 8; ++o) s += pslot[o * SS_ST + t];
            s_tile[(t >> 6) * SS_ST + 64 * tt + (t & 63)] = s;
        }
        __syncthreads();                       // B1': stage + pslot reuse safe
    }

    // ---- Phase B: softmax (wave w = q-row w), attn write ----
    float x[8];
    float m = -1e30f;
#pragma unroll
    for (int j = 0; j < 8; ++j) {
        x[j] = s_tile[w * SS_ST + 64 * j + lane];
        m = fmaxf(m, x[j]);
    }
#pragma unroll
    for (int off = 32; off; off >>= 1) m = fmaxf(m, __shfl_xor(m, off));

    float sum = 0.f;
#pragma unroll
    for (int j = 0; j < 8; ++j) { x[j] = fast_exp2((x[j] - m) * LOG2E); sum += x[j]; }
#pragma unroll
    for (int off = 32; off; off >>= 1) sum += __shfl_xor(sum, off);
    const float inv = fast_rcp(sum);

    float* arow = attn + (size_t)(b * 512 + q0 + w) * 512;
#pragma unroll
    for (int j = 0; j < 8; ++j) {
        s_tile[w * SS_ST + 64 * j + lane] = x[j];   // raw exp for PV
        arow[64 * j + lane] = x[j] * inv;
    }
    if (lane == 0) inv_lds[w] = inv;
    __syncthreads();

    // ---- Phase C: PV, wave w owns k in [64w, 64w+64) ----
    float4 acc[8];
#pragma unroll
    for (int r = 0; r < 8; ++r) acc[r] = make_float4(0.f, 0.f, 0.f, 0.f);

    const float* vbase = value + (size_t)(b * 512 + 64 * w) * 256;
    for (int k4 = 0; k4 < 64; k4 += 4) {
        const float4 v0 = *(const float4*)&vbase[(k4 + 0) * 256 + lane * 4];
        const float4 v1 = *(const float4*)&vbase[(k4 + 1) * 256 + lane * 4];
        const float4 v2 = *(const float4*)&vbase[(k4 + 2) * 256 + lane * 4];
        const float4 v3 = *(const float4*)&vbase[(k4 + 3) * 256 + lane * 4];
#pragma unroll
        for (int r = 0; r < 8; ++r) {
            const float4 s4 = *(const float4*)&s_tile[r * SS_ST + 64 * w + k4];
            acc[r].x = fmaf(s4.x, v0.x, acc[r].x); acc[r].y = fmaf(s4.x, v0.y, acc[r].y);
            acc[r].z = fmaf(s4.x, v0.z, acc[r].z); acc[r].w = fmaf(s4.x, v0.w, acc[r].w);
            acc[r].x = fmaf(s4.y, v1.x, acc[r].x); acc[r].y = fmaf(s4.y, v1.y, acc[r].y);
            acc[r].z = fmaf(s4.y, v1.z, acc[r].z); acc[r].w = fmaf(s4.y, v1.w, acc[r].w);
            acc[r].x = fmaf(s4.z, v2.x, acc[r].x); acc[r].y = fmaf(s4.z, v2.y, acc[r].y);
            acc[r].z = fmaf(s4.z, v2.z, acc[r].z); acc[r].w = fmaf(s4.z, v2.w, acc[r].w);
            acc[r].x = fmaf(s4.w, v3.x, acc[r].x); acc[r].y = fmaf(s4.w, v3.y, acc[r].y);
            acc[r].z = fmaf(s4.w, v3.z, acc[r].z); acc[r].w = fmaf(s4.w, v3.w, acc[r].w);
        }
    }

    // ---- Phase D: tree reduce 8 -> 1 (red = ek_lds, free after Phase A) ----
    float* red = ek_lds;
    if (w >= 4) {
#pragma unroll
        for (int r = 0; r < 8; ++r)
            *(float4*)&red[((w - 4) * 8 + r) * 256 + lane * 4] = acc[r];
    }
    __syncthreads();
    if (w < 4) {
#pragma unroll
        for (int r = 0; r < 8; ++r) {
            const float4 o = *(const float4*)&red[(w * 8 + r) * 256 + lane * 4];
            acc[r].x += o.x; acc[r].y += o.y; acc[r].z += o.z; acc[r].w += o.w;
        }
    }
    __syncthreads();
    if (w >= 2 && w < 4) {
#pragma unroll
        for (int r = 0; r < 8; ++r)
            *(float4*)&red[((w - 2) * 8 + r) * 256 + lane * 4] = acc[r];
    }
    __syncthreads();
    if (w < 2) {
#pragma unroll
        for (int r = 0; r < 8; ++r) {
            const float4 o = *(const float4*)&red[(w * 8 + r) * 256 + lane * 4];
            acc[r].x += o.x; acc[r].y += o.y; acc[r].z += o.z; acc[r].w += o.w;
        }
    }
    __syncthreads();
    if (w == 1) {
#pragma unroll
        for (int r = 0; r < 8; ++r)
            *(float4*)&red[r * 256 + lane * 4] = acc[r];
    }
    __syncthreads();
    if (w == 0) {
#pragma unroll
        for (int r = 0; r < 8; ++r) {
            const float4 o = *(const float4*)&red[r * 256 + lane * 4];
            const float iv = inv_lds[r];
            float4 res;
            res.x = (acc[r].x + o.x) * iv;
            res.y = (acc[r].y + o.y) * iv;
            res.z = (acc[r].z + o.z) * iv;
            res.w = (acc[r].w + o.w) * iv;
            *(float4*)&out[(size_t)(b * 512 + q0 + r) * 256 + lane * 4] = res;
        }
    }
}

extern "C" void kernel_launch(void* const* d_in, const int* in_sizes, int n_in,
                              void* d_out, int out_size, void* d_ws, size_t ws_size,
                              hipStream_t stream) {
    const float* query = (const float*)d_in[0];
    const float* value = (const float*)d_in[1];
    const float* Wq    = (const float*)d_in[2];
    const float* Wv    = (const float*)d_in[3];
    const float* scale = (const float*)d_in[4];

    float* out0 = (float*)d_out;                 // [4,512,256]
    float* attn = out0 + 4 * 512 * 256;          // [4,512,512]

    float* eq = (float*)d_ws;                    // [2048,256]
    float* ek = eq + 2048 * 256;                 // [2048,256]

    proj_kernel<<<512, 256, 0, stream>>>(query, value, Wq, Wv, eq, ek);
    fused_kernel<<<dim3(64, 4), 512, 0, stream>>>(eq, ek, scale, value, attn, out0);
}